// Round 1
// baseline (836.026 us; speedup 1.0000x reference)
//
#include <hip/hip_runtime.h>
#include <hip/hip_bf16.h>

#define L_TOT (1 << 18)       // 262144 positions
#define L_SHIFT 18
#define NHEAD 8
#define DHEAD 16
#define DMODEL 128
#define EPSF 1e-6f

__device__ __forceinline__ float sigm(float x) {
    return 1.0f / (1.0f + __expf(-x));
}

// ---------------------------------------------------------------------------
// K1: per-position stats. Each thread owns one l.
// Outputs: scale[h*L+l] = sigmoid(conserved_sink)*sink_incoming
//          wbuf[h*L+l]  = exp(clip(conserved_source,-1,1))
//          sumexp[h]   += block partials (global atomics)
// ---------------------------------------------------------------------------
__global__ __launch_bounds__(256) void k1_stats(
        const float* __restrict__ Q, const float* __restrict__ K,
        float* __restrict__ scale_o, float* __restrict__ wbuf,
        float* __restrict__ sumexp) {
    const int l = blockIdx.x * 256 + threadIdx.x;

    __hip_bfloat162 qb[64], kb[64];    // packed sigmoid(q), sigmoid(k)
    float ks[DHEAD], qs[DHEAD];
#pragma unroll
    for (int d = 0; d < DHEAD; ++d) { ks[d] = 0.f; qs[d] = 0.f; }

    // pass 1: load + sigmoid + head-sums, pack bf16 for reuse
#pragma unroll
    for (int h = 0; h < NHEAD; ++h) {
#pragma unroll
        for (int d = 0; d < DHEAD; d += 2) {
            const int p = h * DHEAD + d;
            float q0 = sigm(Q[(p << L_SHIFT) + l]);
            float q1 = sigm(Q[((p + 1) << L_SHIFT) + l]);
            float k0 = sigm(K[(p << L_SHIFT) + l]);
            float k1v = sigm(K[((p + 1) << L_SHIFT) + l]);
            qs[d] += q0; qs[d + 1] += q1;
            ks[d] += k0; ks[d + 1] += k1v;
            qb[p >> 1] = __hip_bfloat162{__float2bfloat16(q0), __float2bfloat16(q1)};
            kb[p >> 1] = __hip_bfloat162{__float2bfloat16(k0), __float2bfloat16(k1v)};
        }
    }

    // sink_incoming (si), source_outgoing (so)
    float si[NHEAD], so[NHEAD];
#pragma unroll
    for (int h = 0; h < NHEAD; ++h) {
        float sa_ = 0.f, sb_ = 0.f;
#pragma unroll
        for (int d = 0; d < DHEAD; d += 2) {
            __hip_bfloat162 qq = qb[h * 8 + (d >> 1)];
            __hip_bfloat162 kk = kb[h * 8 + (d >> 1)];
            sa_ += (__bfloat162float(qq.x) + EPSF) * (ks[d] + EPSF)
                 + (__bfloat162float(qq.y) + EPSF) * (ks[d + 1] + EPSF);
            sb_ += (__bfloat162float(kk.x) + EPSF) * (qs[d] + EPSF)
                 + (__bfloat162float(kk.y) + EPSF) * (qs[d + 1] + EPSF);
        }
        si[h] = 1.f / sa_;
        so[h] = 1.f / sb_;
    }

    // kso[d] = sum_h sigk[h,d]*so[h];  qsi[d] = sum_h sigq[h,d]*si[h]
    float kso[DHEAD], qsi[DHEAD];
#pragma unroll
    for (int d = 0; d < DHEAD; ++d) { kso[d] = 0.f; qsi[d] = 0.f; }
#pragma unroll
    for (int h = 0; h < NHEAD; ++h) {
#pragma unroll
        for (int d = 0; d < DHEAD; d += 2) {
            __hip_bfloat162 qq = qb[h * 8 + (d >> 1)];
            __hip_bfloat162 kk = kb[h * 8 + (d >> 1)];
            kso[d]     += __bfloat162float(kk.x) * so[h];
            kso[d + 1] += __bfloat162float(kk.y) * so[h];
            qsi[d]     += __bfloat162float(qq.x) * si[h];
            qsi[d + 1] += __bfloat162float(qq.y) * si[h];
        }
    }

    // conserved_sink / conserved_source, outputs
    float sloc[NHEAD];
#pragma unroll
    for (int h = 0; h < NHEAD; ++h) {
        float ck = 0.f, cs = 0.f;
#pragma unroll
        for (int d = 0; d < DHEAD; d += 2) {
            __hip_bfloat162 qq = qb[h * 8 + (d >> 1)];
            __hip_bfloat162 kk = kb[h * 8 + (d >> 1)];
            ck += (__bfloat162float(qq.x) + EPSF) * (kso[d] + EPSF)
                + (__bfloat162float(qq.y) + EPSF) * (kso[d + 1] + EPSF);
            cs += (__bfloat162float(kk.x) + EPSF) * (qsi[d] + EPSF)
                + (__bfloat162float(kk.y) + EPSF) * (qsi[d + 1] + EPSF);
        }
        cs = fminf(fmaxf(cs, -1.f), 1.f);
        float e = __expf(cs);
        wbuf[(h << L_SHIFT) + l] = e;
        scale_o[(h << L_SHIFT) + l] = sigm(ck) * si[h];
        sloc[h] = e;
    }

    // block-level sumexp reduction -> global atomics
    __shared__ float red[NHEAD];
    if (threadIdx.x < NHEAD) red[threadIdx.x] = 0.f;
    __syncthreads();
    const int lane = threadIdx.x & 63;
#pragma unroll
    for (int h = 0; h < NHEAD; ++h) {
        float v = sloc[h];
#pragma unroll
        for (int o = 32; o >= 1; o >>= 1) v += __shfl_xor(v, o, 64);
        if (lane == 0) atomicAdd(&red[h], v);
    }
    __syncthreads();
    if (threadIdx.x < NHEAD) atomicAdd(&sumexp[threadIdx.x], red[threadIdx.x]);
}

// ---------------------------------------------------------------------------
// K2: kv[h,d,m] = sum_l sigmoid(k[h,l,d]) * w[h,l] * v[h,l,m]
// grid = 8 heads * 128 blocks; block owns 2048 l's; thread owns (d,m).
// ---------------------------------------------------------------------------
__global__ __launch_bounds__(256) void k2_kv(
        const float* __restrict__ Kg, const float* __restrict__ Vg,
        const float* __restrict__ wg, float* __restrict__ kv) {
    const int b = blockIdx.x;
    const int h = b >> 7;
    const int blk = b & 127;
    const int t = threadIdx.x;
    const int dd = t >> 4, m = t & 15;

    __shared__ float A[16][129];
    __shared__ float Vv[16][129];
    __shared__ float wl[128];

    const int baseK = (h * DHEAD) << L_SHIFT;
    float acc = 0.f;

    for (int ch = 0; ch < 16; ++ch) {
        const int l0 = blk * 2048 + ch * 128;
        __syncthreads();                       // readers done with prev tile
        if (t < 128) wl[t] = wg[(h << L_SHIFT) + l0 + t];
        __syncthreads();                       // wl visible
#pragma unroll
        for (int i = 0; i < 8; ++i) {
            const int e = t + i * 256;
            const int r = e >> 7, c = e & 127;
            A[r][c] = sigm(Kg[baseK + (r << L_SHIFT) + l0 + c]) * wl[c];
            Vv[r][c] = Vg[baseK + (r << L_SHIFT) + l0 + c];
        }
        __syncthreads();                       // tile ready
#pragma unroll 4
        for (int c = 0; c < 128; ++c) acc += A[dd][c] * Vv[m][c];
    }
    atomicAdd(&kv[h * 256 + dd * 16 + m], acc);
}

// ---------------------------------------------------------------------------
// K3: WkvT[p][dim] = sum_m W[dim, h*16+m] * kv[h,dd,m] * (L/sumexp[h]),
//     p = h*16+dd.  8 blocks (one head each) x 256 threads.
// ---------------------------------------------------------------------------
__global__ __launch_bounds__(256) void k3_wkv(
        const float* __restrict__ Wg, const float* __restrict__ kv,
        const float* __restrict__ sumexp, float* __restrict__ WkvT) {
    const int hb = blockIdx.x;
    const int t = threadIdx.x;
    __shared__ float kvf[256];
    const float s = (float)L_TOT / sumexp[hb];
    kvf[t] = kv[hb * 256 + t] * s;
    __syncthreads();
#pragma unroll
    for (int i = 0; i < 8; ++i) {
        const int j = t + i * 256;            // 0..2047
        const int dim = j & 127, pr = j >> 7; // pr: 0..15
        float a = 0.f;
#pragma unroll
        for (int mm = 0; mm < 16; ++mm)
            a += Wg[dim * 128 + hb * 16 + mm] * kvf[pr * 16 + mm];
        WkvT[(hb * 16 + pr) * 128 + dim] = a;
    }
}

// ---------------------------------------------------------------------------
// K4: out[dim,l] = b[dim] + sum_p WkvT[p][dim] * (sigmoid(q[p,l]) * scale[p>>4,l])
// ---------------------------------------------------------------------------
__global__ __launch_bounds__(256) void k4_out(
        const float* __restrict__ Q, const float* __restrict__ scale_g,
        const float* __restrict__ WkvT, const float* __restrict__ bg,
        float* __restrict__ out) {
    __shared__ float WT[16384];               // 64 KB, [p][dim]
    const int t = threadIdx.x;
#pragma unroll
    for (int i = 0; i < 16; ++i)
        ((float4*)WT)[t + i * 256] = ((const float4*)WkvT)[t + i * 256];
    __syncthreads();

    const int l = blockIdx.x * 256 + t;
    float g[128];
#pragma unroll
    for (int h = 0; h < NHEAD; ++h) {
        const float sc = scale_g[(h << L_SHIFT) + l];
#pragma unroll
        for (int d = 0; d < DHEAD; ++d) {
            const int p = h * DHEAD + d;
            g[p] = sigm(Q[(p << L_SHIFT) + l]) * sc;
        }
    }

    for (int dg = 0; dg < 8; ++dg) {          // 16 output dims per group
        float acc[16];
#pragma unroll
        for (int dd = 0; dd < 16; ++dd) acc[dd] = bg[dg * 16 + dd];
#pragma unroll
        for (int p = 0; p < 128; ++p) {
            const float gv = g[p];
#pragma unroll
            for (int q4 = 0; q4 < 4; ++q4) {
                const float4 wv = *(const float4*)&WT[p * 128 + dg * 16 + q4 * 4];
                acc[q4 * 4 + 0] += wv.x * gv;
                acc[q4 * 4 + 1] += wv.y * gv;
                acc[q4 * 4 + 2] += wv.z * gv;
                acc[q4 * 4 + 3] += wv.w * gv;
            }
        }
#pragma unroll
        for (int dd = 0; dd < 16; ++dd)
            out[((dg * 16 + dd) << L_SHIFT) + l] = acc[dd];
    }
}

// ---------------------------------------------------------------------------
extern "C" void kernel_launch(void* const* d_in, const int* in_sizes, int n_in,
                              void* d_out, int out_size, void* d_ws, size_t ws_size,
                              hipStream_t stream) {
    const float* Q = (const float*)d_in[0];
    const float* K = (const float*)d_in[1];
    const float* V = (const float*)d_in[2];
    const float* W = (const float*)d_in[3];
    const float* B = (const float*)d_in[4];
    float* out = (float*)d_out;
    float* ws = (float*)d_ws;

    // workspace layout (floats)
    float* sumexp = ws + 0;          // 8
    float* kv     = ws + 8;          // 2048
    float* WkvT   = ws + 2064;       // 16384
    float* scale  = ws + 18560;      // 8*L
    float* wbuf   = scale + 8 * L_TOT; // 8*L

    hipMemsetAsync(sumexp, 0, 2056 * sizeof(float), stream);

    k1_stats<<<L_TOT / 256, 256, 0, stream>>>(Q, K, scale, wbuf, sumexp);
    k2_kv<<<NHEAD * 128, 256, 0, stream>>>(K, V, wbuf, kv);
    k3_wkv<<<NHEAD, 256, 0, stream>>>(W, kv, sumexp, WkvT);
    k4_out<<<L_TOT / 256, 256, 0, stream>>>(Q, scale, WkvT, B, out);
}

// Round 2
// 310.546 us; speedup vs baseline: 2.6921x; 2.6921x over previous
//
#include <hip/hip_runtime.h>
#include <hip/hip_bf16.h>

#define L_TOT (1 << 18)       // 262144 positions
#define L_SHIFT 18
#define NHEAD 8
#define DHEAD 16
#define DMODEL 128
#define EPSF 1e-6f

__device__ __forceinline__ float frcp(float x) { return __builtin_amdgcn_rcpf(x); }
__device__ __forceinline__ float sigm(float x) { return frcp(1.0f + __expf(-x)); }

// sum over each aligned 16-lane group, result broadcast to all 16 lanes.
// xor1, xor2 via quad_perm; xor4-equiv via ROW_HALF_MIRROR; xor8-equiv via ROW_MIRROR.
__device__ __forceinline__ float wsum16(float x) {
    x += __int_as_float(__builtin_amdgcn_update_dpp(0, __float_as_int(x), 0xB1, 0xf, 0xf, true));
    x += __int_as_float(__builtin_amdgcn_update_dpp(0, __float_as_int(x), 0x4E, 0xf, 0xf, true));
    x += __int_as_float(__builtin_amdgcn_update_dpp(0, __float_as_int(x), 0x141, 0xf, 0xf, true));
    x += __int_as_float(__builtin_amdgcn_update_dpp(0, __float_as_int(x), 0x140, 0xf, 0xf, true));
    return x;
}
// x += lanes xor 16 (ds_swizzle bitmode), then xor 32 (bpermute)
__device__ __forceinline__ float xadd16(float x) {
    return x + __int_as_float(__builtin_amdgcn_ds_swizzle(__float_as_int(x), 0x401f));
}
__device__ __forceinline__ float xadd32(float x, int bpa) {
    return x + __int_as_float(__builtin_amdgcn_ds_bpermute(bpa, __float_as_int(x)));
}

// ---------------------------------------------------------------------------
// K1: per-position stats, wave-transposed. Block = 256 thr, 64 l's per block.
// LDS tile sp[64 l][128 p] holds (sigk|sigq) packed bf16, col-swizzled.
// Outputs: scale[h*L+l], wbuf[h*L+l] = exp(clip(cs)), sep[block*8+h] partials.
// ---------------------------------------------------------------------------
__global__ __launch_bounds__(256) void k1_stats(
        const float* __restrict__ Q, const float* __restrict__ K,
        float* __restrict__ scale_o, float* __restrict__ wbuf,
        float* __restrict__ sep) {
    __shared__ unsigned int sp[64][128];   // 32 KB
    __shared__ float wlds[8][64];
    __shared__ float slds[8][64];
    __shared__ float hred[32];

    const int t = threadIdx.x;
    const int l0 = blockIdx.x * 64;
    const int c = t & 63;                  // column this thread loads
    const int w = t >> 6;                  // wave id
    const int sw = (c & 31) << 2;          // per-row col swizzle (bits 2..6)

    // ---- load + sigmoid + pack bf16 pairs (rn) ----
#pragma unroll
    for (int i = 0; i < 8; ++i) {
        const int pb = 4 * (w + 4 * i);    // row group 0..124
        unsigned int pk[4];
#pragma unroll
        for (int r = 0; r < 4; ++r) {
            float qv = sigm(Q[((pb + r) << L_SHIFT) + l0 + c]);
            float kv = sigm(K[((pb + r) << L_SHIFT) + l0 + c]);
            unsigned qu = __float_as_uint(qv) + 0x8000u;
            unsigned ku = __float_as_uint(kv) + 0x8000u;
            pk[r] = (ku & 0xffff0000u) | (qu >> 16);
        }
        *(uint4*)(&sp[c][pb ^ sw]) = make_uint4(pk[0], pk[1], pk[2], pk[3]);
    }
    __syncthreads();

    // ---- compute: wave w handles l_loc = w*16 + j ----
    const int lane = t & 63;
    const int bpa = (lane ^ 32) << 2;      // bpermute byte addr for xor32
    float acc0 = 0.f, acc1 = 0.f;

    for (int j = 0; j < 16; ++j) {
        const int cl = w * 16 + j;
        const int swl = (cl & 31) << 2;
        const unsigned u0 = sp[cl][lane ^ swl];
        const unsigned u1 = sp[cl][(lane + 64) ^ swl];
        const float sq0 = __uint_as_float(u0 << 16);
        const float sk0 = __uint_as_float(u0 & 0xffff0000u);
        const float sq1 = __uint_as_float(u1 << 16);
        const float sk1 = __uint_as_float(u1 & 0xffff0000u);

        // head sums over h (lanes {d, d+16, d+32, d+48} x 2 regs)
        float tks = xadd32(xadd16(sk0 + sk1), bpa);   // ks[d], bcast
        float tqs = xadd32(xadd16(sq0 + sq1), bpa);   // qs[d], bcast

        // si/so per h (16-lane group reductions, DPP)
        const float si0 = frcp(wsum16((sq0 + EPSF) * (tks + EPSF)));
        const float si1 = frcp(wsum16((sq1 + EPSF) * (tks + EPSF)));
        const float so0 = frcp(wsum16((sk0 + EPSF) * (tqs + EPSF)));
        const float so1 = frcp(wsum16((sk1 + EPSF) * (tqs + EPSF)));

        // kso[d], qsi[d]
        const float tkso = xadd32(xadd16(sk0 * so0 + sk1 * so1), bpa);
        const float tqsi = xadd32(xadd16(sq0 * si0 + sq1 * si1), bpa);

        // conserved sink / source per h
        const float ck0 = wsum16((sq0 + EPSF) * (tkso + EPSF));
        const float ck1 = wsum16((sq1 + EPSF) * (tkso + EPSF));
        float cs0 = wsum16((sk0 + EPSF) * (tqsi + EPSF));
        float cs1 = wsum16((sk1 + EPSF) * (tqsi + EPSF));
        cs0 = fminf(fmaxf(cs0, -1.f), 1.f);
        cs1 = fminf(fmaxf(cs1, -1.f), 1.f);
        const float e0 = __expf(cs0);
        const float e1 = __expf(cs1);
        acc0 += e0; acc1 += e1;
        const float sc0 = sigm(ck0) * si0;
        const float sc1 = sigm(ck1) * si1;

        if ((lane & 15) == 0) {
            const int h = lane >> 4;
            wlds[h][cl] = e0;  wlds[h + 4][cl] = e1;
            slds[h][cl] = sc0; slds[h + 4][cl] = sc1;
        }
    }
    if ((lane & 15) == 0) {
        const int h = lane >> 4;
        hred[w * 8 + h] = acc0;
        hred[w * 8 + h + 4] = acc1;
    }
    __syncthreads();

    // ---- coalesced output ----
#pragma unroll
    for (int i = 0; i < 2; ++i) {
        const int idx = t + i * 256;       // 0..511
        const int h = idx >> 6, cc = idx & 63;
        wbuf[(h << L_SHIFT) + l0 + cc] = wlds[h][cc];
        scale_o[(h << L_SHIFT) + l0 + cc] = slds[h][cc];
    }
    if (t < 8)
        sep[blockIdx.x * 8 + t] = hred[t] + hred[8 + t] + hred[16 + t] + hred[24 + t];
}

// ---------------------------------------------------------------------------
// K2: kv[h,d,m] = sum_l sigmoid(k[h,l,d]) * w[h,l] * v[h,l,m]
// grid = 8 heads * 128 blocks; block owns 2048 l's; thread owns (d,m).
// ---------------------------------------------------------------------------
__global__ __launch_bounds__(256) void k2_kv(
        const float* __restrict__ Kg, const float* __restrict__ Vg,
        const float* __restrict__ wg, float* __restrict__ kv) {
    const int b = blockIdx.x;
    const int h = b >> 7;
    const int blk = b & 127;
    const int t = threadIdx.x;
    const int dd = t >> 4, m = t & 15;

    __shared__ float A[16][132];
    __shared__ float Vv[16][132];
    __shared__ float wl[128];

    const int baseK = (h * DHEAD) << L_SHIFT;
    float acc = 0.f;

    for (int ch = 0; ch < 16; ++ch) {
        const int l0 = blk * 2048 + ch * 128;
        __syncthreads();                       // readers done with prev tile
        if (t < 128) wl[t] = wg[(h << L_SHIFT) + l0 + t];
        __syncthreads();                       // wl visible
#pragma unroll
        for (int i = 0; i < 8; ++i) {
            const int e = t + i * 256;
            const int r = e >> 7, cc = e & 127;
            A[r][cc] = sigm(Kg[baseK + (r << L_SHIFT) + l0 + cc]) * wl[cc];
            Vv[r][cc] = Vg[baseK + (r << L_SHIFT) + l0 + cc];
        }
        __syncthreads();                       // tile ready
#pragma unroll
        for (int c4 = 0; c4 < 32; ++c4) {
            const float4 av = *(const float4*)&A[dd][c4 * 4];
            const float4 vv = *(const float4*)&Vv[m][c4 * 4];
            acc += av.x * vv.x + av.y * vv.y + av.z * vv.z + av.w * vv.w;
        }
    }
    atomicAdd(&kv[h * 256 + dd * 16 + m], acc);
}

// ---------------------------------------------------------------------------
// K3: reduce sep -> sumexp per head; WkvT[p][dim] = sum_m W[dim,h*16+m]*kv*s
// 8 blocks (one head each) x 256 threads.
// ---------------------------------------------------------------------------
__global__ __launch_bounds__(256) void k3_wkv(
        const float* __restrict__ Wg, const float* __restrict__ kv,
        const float* __restrict__ sep, float* __restrict__ WkvT) {
    const int hb = blockIdx.x;
    const int t = threadIdx.x;
    __shared__ float kvf[256];
    __shared__ float redl[4];

    float p = 0.f;
#pragma unroll
    for (int i = 0; i < 16; ++i) p += sep[(t + i * 256) * 8 + hb];
#pragma unroll
    for (int o = 32; o >= 1; o >>= 1) p += __shfl_xor(p, o, 64);
    if ((t & 63) == 0) redl[t >> 6] = p;
    __syncthreads();
    const float s = (float)L_TOT / (redl[0] + redl[1] + redl[2] + redl[3]);

    kvf[t] = kv[hb * 256 + t] * s;
    __syncthreads();
#pragma unroll
    for (int i = 0; i < 8; ++i) {
        const int j = t + i * 256;            // 0..2047
        const int dim = j & 127, pr = j >> 7; // pr: 0..15
        float a = 0.f;
#pragma unroll
        for (int mm = 0; mm < 16; ++mm)
            a += Wg[dim * 128 + hb * 16 + mm] * kvf[pr * 16 + mm];
        WkvT[(hb * 16 + pr) * 128 + dim] = a;
    }
}

// ---------------------------------------------------------------------------
// K4: out[dim,l] = b[dim] + sum_p WkvT[p][dim] * (sigmoid(q[p,l]) * scale[p>>4,l])
// ---------------------------------------------------------------------------
__global__ __launch_bounds__(256) void k4_out(
        const float* __restrict__ Q, const float* __restrict__ scale_g,
        const float* __restrict__ WkvT, const float* __restrict__ bg,
        float* __restrict__ out) {
    __shared__ float WT[16384];               // 64 KB, [p][dim]
    const int t = threadIdx.x;
#pragma unroll
    for (int i = 0; i < 16; ++i)
        ((float4*)WT)[t + i * 256] = ((const float4*)WkvT)[t + i * 256];
    __syncthreads();

    const int l = blockIdx.x * 256 + t;
    float g[128];
#pragma unroll
    for (int h = 0; h < NHEAD; ++h) {
        const float sc = scale_g[(h << L_SHIFT) + l];
#pragma unroll
        for (int d = 0; d < DHEAD; ++d) {
            const int p = h * DHEAD + d;
            g[p] = sigm(Q[(p << L_SHIFT) + l]) * sc;
        }
    }

    for (int dg = 0; dg < 8; ++dg) {          // 16 output dims per group
        float acc[16];
#pragma unroll
        for (int dd = 0; dd < 16; ++dd) acc[dd] = bg[dg * 16 + dd];
#pragma unroll
        for (int p = 0; p < 128; ++p) {
            const float gv = g[p];
#pragma unroll
            for (int q4 = 0; q4 < 4; ++q4) {
                const float4 wv = *(const float4*)&WT[p * 128 + dg * 16 + q4 * 4];
                acc[q4 * 4 + 0] += wv.x * gv;
                acc[q4 * 4 + 1] += wv.y * gv;
                acc[q4 * 4 + 2] += wv.z * gv;
                acc[q4 * 4 + 3] += wv.w * gv;
            }
        }
#pragma unroll
        for (int dd = 0; dd < 16; ++dd)
            out[((dg * 16 + dd) << L_SHIFT) + l] = acc[dd];
    }
}

// ---------------------------------------------------------------------------
extern "C" void kernel_launch(void* const* d_in, const int* in_sizes, int n_in,
                              void* d_out, int out_size, void* d_ws, size_t ws_size,
                              hipStream_t stream) {
    const float* Q = (const float*)d_in[0];
    const float* K = (const float*)d_in[1];
    const float* V = (const float*)d_in[2];
    const float* W = (const float*)d_in[3];
    const float* B = (const float*)d_in[4];
    float* out = (float*)d_out;
    float* ws = (float*)d_ws;

    // workspace layout (floats)
    float* kv    = ws;                    // 2048
    float* WkvT  = ws + 2048;             // 16384
    float* sep   = ws + 18432;            // 4096*8 = 32768
    float* scale = ws + 51200;            // 8*L
    float* wbuf  = scale + 8 * L_TOT;     // 8*L

    hipMemsetAsync(kv, 0, 2048 * sizeof(float), stream);

    k1_stats<<<L_TOT / 64, 256, 0, stream>>>(Q, K, scale, wbuf, sep);
    k2_kv<<<NHEAD * 128, 256, 0, stream>>>(K, V, wbuf, kv);
    k3_wkv<<<NHEAD, 256, 0, stream>>>(W, kv, sep, WkvT);
    k4_out<<<L_TOT / 256, 256, 0, stream>>>(Q, scale, WkvT, B, out);
}

// Round 3
// 217.179 us; speedup vs baseline: 3.8495x; 1.4299x over previous
//
#include <hip/hip_runtime.h>
#include <hip/hip_bf16.h>

#define L_TOT (1 << 18)       // 262144 positions
#define L_SHIFT 18
#define NHEAD 8
#define DHEAD 16
#define DMODEL 128
#define EPSF 1e-6f

typedef float f32x4 __attribute__((ext_vector_type(4)));
typedef short bf16x8 __attribute__((ext_vector_type(8)));

__device__ __forceinline__ float frcp(float x) { return __builtin_amdgcn_rcpf(x); }
__device__ __forceinline__ float sigm(float x) { return frcp(1.0f + __expf(-x)); }
__device__ __forceinline__ unsigned short f2bf(float f) {
    return (unsigned short)((__float_as_uint(f) + 0x8000u) >> 16);
}

// sum over each aligned 16-lane group, result broadcast to all 16 lanes.
__device__ __forceinline__ float wsum16(float x) {
    x += __int_as_float(__builtin_amdgcn_update_dpp(0, __float_as_int(x), 0xB1, 0xf, 0xf, true));
    x += __int_as_float(__builtin_amdgcn_update_dpp(0, __float_as_int(x), 0x4E, 0xf, 0xf, true));
    x += __int_as_float(__builtin_amdgcn_update_dpp(0, __float_as_int(x), 0x141, 0xf, 0xf, true));
    x += __int_as_float(__builtin_amdgcn_update_dpp(0, __float_as_int(x), 0x140, 0xf, 0xf, true));
    return x;
}
// x += lanes xor 16 (ds_swizzle bitmode), then xor 32 (bpermute)
__device__ __forceinline__ float xadd16(float x) {
    return x + __int_as_float(__builtin_amdgcn_ds_swizzle(__float_as_int(x), 0x401f));
}
__device__ __forceinline__ float xadd32(float x, int bpa) {
    return x + __int_as_float(__builtin_amdgcn_ds_bpermute(bpa, __float_as_int(x)));
}

// ---------------------------------------------------------------------------
// K1: per-position stats, wave-transposed. Block = 256 thr, 64 l's per block.
// ---------------------------------------------------------------------------
__global__ __launch_bounds__(256) void k1_stats(
        const float* __restrict__ Q, const float* __restrict__ K,
        float* __restrict__ scale_o, float* __restrict__ wbuf,
        float* __restrict__ sep) {
    __shared__ unsigned int sp[64][128];   // 32 KB
    __shared__ float wlds[8][64];
    __shared__ float slds[8][64];
    __shared__ float hred[32];

    const int t = threadIdx.x;
    const int l0 = blockIdx.x * 64;
    const int c = t & 63;                  // column this thread loads
    const int w = t >> 6;                  // wave id
    const int sw = (c & 31) << 2;          // per-row col swizzle (bits 2..6)

    // ---- load + sigmoid + pack bf16 pairs ----
#pragma unroll
    for (int i = 0; i < 8; ++i) {
        const int pb = 4 * (w + 4 * i);    // row group 0..124
        unsigned int pk[4];
#pragma unroll
        for (int r = 0; r < 4; ++r) {
            float qv = sigm(Q[((pb + r) << L_SHIFT) + l0 + c]);
            float kv = sigm(K[((pb + r) << L_SHIFT) + l0 + c]);
            unsigned qu = __float_as_uint(qv) + 0x8000u;
            unsigned ku = __float_as_uint(kv) + 0x8000u;
            pk[r] = (ku & 0xffff0000u) | (qu >> 16);
        }
        *(uint4*)(&sp[c][pb ^ sw]) = make_uint4(pk[0], pk[1], pk[2], pk[3]);
    }
    __syncthreads();

    // ---- compute: wave w handles l_loc = w*16 + j ----
    const int lane = t & 63;
    const int bpa = (lane ^ 32) << 2;      // bpermute byte addr for xor32
    float acc0 = 0.f, acc1 = 0.f;

    for (int j = 0; j < 16; ++j) {
        const int cl = w * 16 + j;
        const int swl = (cl & 31) << 2;
        const unsigned u0 = sp[cl][lane ^ swl];
        const unsigned u1 = sp[cl][(lane + 64) ^ swl];
        const float sq0 = __uint_as_float(u0 << 16);
        const float sk0 = __uint_as_float(u0 & 0xffff0000u);
        const float sq1 = __uint_as_float(u1 << 16);
        const float sk1 = __uint_as_float(u1 & 0xffff0000u);

        float tks = xadd32(xadd16(sk0 + sk1), bpa);   // ks[d], bcast
        float tqs = xadd32(xadd16(sq0 + sq1), bpa);   // qs[d], bcast

        const float si0 = frcp(wsum16((sq0 + EPSF) * (tks + EPSF)));
        const float si1 = frcp(wsum16((sq1 + EPSF) * (tks + EPSF)));
        const float so0 = frcp(wsum16((sk0 + EPSF) * (tqs + EPSF)));
        const float so1 = frcp(wsum16((sk1 + EPSF) * (tqs + EPSF)));

        const float tkso = xadd32(xadd16(sk0 * so0 + sk1 * so1), bpa);
        const float tqsi = xadd32(xadd16(sq0 * si0 + sq1 * si1), bpa);

        const float ck0 = wsum16((sq0 + EPSF) * (tkso + EPSF));
        const float ck1 = wsum16((sq1 + EPSF) * (tkso + EPSF));
        float cs0 = wsum16((sk0 + EPSF) * (tqsi + EPSF));
        float cs1 = wsum16((sk1 + EPSF) * (tqsi + EPSF));
        cs0 = fminf(fmaxf(cs0, -1.f), 1.f);
        cs1 = fminf(fmaxf(cs1, -1.f), 1.f);
        const float e0 = __expf(cs0);
        const float e1 = __expf(cs1);
        acc0 += e0; acc1 += e1;
        const float sc0 = sigm(ck0) * si0;
        const float sc1 = sigm(ck1) * si1;

        if ((lane & 15) == 0) {
            const int h = lane >> 4;
            wlds[h][cl] = e0;  wlds[h + 4][cl] = e1;
            slds[h][cl] = sc0; slds[h + 4][cl] = sc1;
        }
    }
    if ((lane & 15) == 0) {
        const int h = lane >> 4;
        hred[w * 8 + h] = acc0;
        hred[w * 8 + h + 4] = acc1;
    }
    __syncthreads();

    // ---- coalesced output ----
#pragma unroll
    for (int i = 0; i < 2; ++i) {
        const int idx = t + i * 256;       // 0..511
        const int h = idx >> 6, cc = idx & 63;
        wbuf[(h << L_SHIFT) + l0 + cc] = wlds[h][cc];
        scale_o[(h << L_SHIFT) + l0 + cc] = slds[h][cc];
    }
    if (t < 8)
        sep[blockIdx.x * 8 + t] = hred[t] + hred[8 + t] + hred[16 + t] + hred[24 + t];
}

// ---------------------------------------------------------------------------
// K2: kv[h,d,m] = sum_l sigmoid(k[h,l,d]) * w[h,l] * v[h,l,m]
// ---------------------------------------------------------------------------
__global__ __launch_bounds__(256) void k2_kv(
        const float* __restrict__ Kg, const float* __restrict__ Vg,
        const float* __restrict__ wg, float* __restrict__ kv) {
    const int b = blockIdx.x;
    const int h = b >> 7;
    const int blk = b & 127;
    const int t = threadIdx.x;
    const int dd = t >> 4, m = t & 15;

    __shared__ float A[16][132];
    __shared__ float Vv[16][132];
    __shared__ float wl[128];

    const int baseK = (h * DHEAD) << L_SHIFT;
    float acc = 0.f;

    for (int ch = 0; ch < 16; ++ch) {
        const int l0 = blk * 2048 + ch * 128;
        __syncthreads();                       // readers done with prev tile
        if (t < 128) wl[t] = wg[(h << L_SHIFT) + l0 + t];
        __syncthreads();                       // wl visible
#pragma unroll
        for (int i = 0; i < 8; ++i) {
            const int e = t + i * 256;
            const int r = e >> 7, cc = e & 127;
            A[r][cc] = sigm(Kg[baseK + (r << L_SHIFT) + l0 + cc]) * wl[cc];
            Vv[r][cc] = Vg[baseK + (r << L_SHIFT) + l0 + cc];
        }
        __syncthreads();                       // tile ready
#pragma unroll
        for (int c4 = 0; c4 < 32; ++c4) {
            const float4 av = *(const float4*)&A[dd][c4 * 4];
            const float4 vv = *(const float4*)&Vv[m][c4 * 4];
            acc += av.x * vv.x + av.y * vv.y + av.z * vv.z + av.w * vv.w;
        }
    }
    atomicAdd(&kv[h * 256 + dd * 16 + m], acc);
}

// ---------------------------------------------------------------------------
// K3: reduce sep -> sumexp; emit Wkv as bf16-packed pairs wkvb[dim][p/2]
// ---------------------------------------------------------------------------
__global__ __launch_bounds__(256) void k3_wkv(
        const float* __restrict__ Wg, const float* __restrict__ kv,
        const float* __restrict__ sep, unsigned* __restrict__ wkvb) {
    const int hb = blockIdx.x;
    const int t = threadIdx.x;
    __shared__ float kvf[256];
    __shared__ float redl[4];

    float p = 0.f;
#pragma unroll
    for (int i = 0; i < 16; ++i) p += sep[(t + i * 256) * 8 + hb];
#pragma unroll
    for (int o = 32; o >= 1; o >>= 1) p += __shfl_xor(p, o, 64);
    if ((t & 63) == 0) redl[t >> 6] = p;
    __syncthreads();
    const float s = (float)L_TOT / (redl[0] + redl[1] + redl[2] + redl[3]);

    kvf[t] = kv[hb * 256 + t] * s;
    __syncthreads();
#pragma unroll
    for (int i = 0; i < 4; ++i) {
        const int j = t + i * 256;              // 0..1023
        const int dim = j & 127, prp = j >> 7;  // prp: 0..7 (pr pairs)
        float a0 = 0.f, a1 = 0.f;
#pragma unroll
        for (int mm = 0; mm < 16; ++mm) {
            const float wv = Wg[dim * 128 + hb * 16 + mm];
            a0 += wv * kvf[(2 * prp) * 16 + mm];
            a1 += wv * kvf[(2 * prp + 1) * 16 + mm];
        }
        wkvb[dim * 64 + hb * 8 + prp] = ((unsigned)f2bf(a1) << 16) | f2bf(a0);
    }
}

// ---------------------------------------------------------------------------
// K4 (MFMA): out[dim,l] = b[dim] + sum_p Wkv[dim][p] * g[p][l]
//   g[p][l] = sigmoid(Q[p][l]) * scale[p>>4][l], bf16.
//   A (Wkv) staged in LDS (68-u32 row stride); B built from global Q.
//   16x16x32 bf16 MFMA: A row=lane&15,k=(lane>>4)*8+j; B col=lane&15 (=l);
//   D col=lane&15, row=(lane>>4)*4+reg.
// ---------------------------------------------------------------------------
__global__ __launch_bounds__(256) void k4_mfma(
        const float* __restrict__ Q, const float* __restrict__ scale_g,
        const unsigned* __restrict__ wkvb, const float* __restrict__ bg,
        float* __restrict__ out) {
    __shared__ unsigned A_lds[128 * 68];     // 34.8 KB
    __shared__ float bias[128];
    const int t = threadIdx.x;

    // stage packed Wkv into LDS
#pragma unroll
    for (int i = 0; i < 8; ++i) {
        const int idx4 = t + i * 256;        // 0..2047 uint4's
        const uint4 v = ((const uint4*)wkvb)[idx4];
        const int row = idx4 >> 4, c4 = idx4 & 15;
        *(uint4*)&A_lds[row * 68 + c4 * 4] = v;
    }
    if (t < 128) bias[t] = bg[t];
    __syncthreads();

    const int w = t >> 6, lane = t & 63;
    const int lq = lane & 15, lh = lane >> 4;

#pragma unroll
    for (int ci = 0; ci < 2; ++ci) {
        const int l = blockIdx.x * 128 + ci * 64 + w * 16 + lq;

        // load Q + scale for all 4 K-steps
        float qv[4][8];
        float scv[4];
#pragma unroll
        for (int ks = 0; ks < 4; ++ks) {
            scv[ks] = scale_g[((ks * 2 + (lane >> 5)) << L_SHIFT) + l];
#pragma unroll
            for (int j = 0; j < 8; ++j) {
                const int p = ks * 32 + lh * 8 + j;
                qv[ks][j] = Q[(p << L_SHIFT) + l];
            }
        }
        bf16x8 bfr[4];
#pragma unroll
        for (int ks = 0; ks < 4; ++ks)
#pragma unroll
            for (int j = 0; j < 8; ++j)
                bfr[ks][j] = (short)f2bf(sigm(qv[ks][j]) * scv[ks]);

        f32x4 acc[8];
#pragma unroll
        for (int mt = 0; mt < 8; ++mt)
            acc[mt] = *(const f32x4*)&bias[mt * 16 + lh * 4];

#pragma unroll
        for (int ks = 0; ks < 4; ++ks) {
#pragma unroll
            for (int mt = 0; mt < 8; ++mt) {
                const int row = mt * 16 + lq;
                const bf16x8 a = *(const bf16x8*)&A_lds[row * 68 + ks * 16 + lh * 4];
                acc[mt] = __builtin_amdgcn_mfma_f32_16x16x32_bf16(a, bfr[ks], acc[mt], 0, 0, 0);
            }
        }

#pragma unroll
        for (int mt = 0; mt < 8; ++mt) {
#pragma unroll
            for (int r = 0; r < 4; ++r) {
                const int dim = mt * 16 + lh * 4 + r;
                out[(dim << L_SHIFT) + l] = acc[mt][r];
            }
        }
    }
}

// ---------------------------------------------------------------------------
extern "C" void kernel_launch(void* const* d_in, const int* in_sizes, int n_in,
                              void* d_out, int out_size, void* d_ws, size_t ws_size,
                              hipStream_t stream) {
    const float* Q = (const float*)d_in[0];
    const float* K = (const float*)d_in[1];
    const float* V = (const float*)d_in[2];
    const float* W = (const float*)d_in[3];
    const float* B = (const float*)d_in[4];
    float* out = (float*)d_out;
    float* ws = (float*)d_ws;

    // workspace layout (floats)
    float* kv       = ws;                     // 2048
    unsigned* wkvb  = (unsigned*)(ws + 2048); // 8192 u32
    float* sep      = ws + 10240;             // 4096*8 = 32768
    float* scale    = ws + 43008;             // 8*L
    float* wbuf     = scale + 8 * L_TOT;      // 8*L

    hipMemsetAsync(kv, 0, 2048 * sizeof(float), stream);

    k1_stats<<<L_TOT / 64, 256, 0, stream>>>(Q, K, scale, wbuf, sep);
    k2_kv<<<NHEAD * 128, 256, 0, stream>>>(K, V, wbuf, kv);
    k3_wkv<<<NHEAD, 256, 0, stream>>>(W, kv, sep, wkvb);
    k4_mfma<<<L_TOT / 128, 256, 0, stream>>>(Q, scale, wkvb, B, out);
}